// Round 7
// baseline (253.241 us; speedup 1.0000x reference)
//
#include <hip/hip_runtime.h>
#include <math.h>

#define S_LEN 2048
#define DMODEL 1024
#define NHEADS 16
#define HDIM 64
#define WIN 256
#define N_QKV 3072

typedef __attribute__((ext_vector_type(8))) short s16x8;
typedef __attribute__((ext_vector_type(8))) _Float16 f16x8;
typedef __attribute__((ext_vector_type(4))) _Float16 f16x4;
typedef __attribute__((ext_vector_type(4))) float f32x4;

__device__ inline unsigned short f2bf(float f) {
    unsigned int u = __float_as_uint(f);
    u += 0x7FFFu + ((u >> 16) & 1u);      // round-to-nearest-even
    return (unsigned short)(u >> 16);
}
__device__ inline float bf2f(unsigned short h) {
    return __uint_as_float(((unsigned int)h) << 16);
}

// ---------------------------------------------------------------------------
// fp32 -> fp16 convert, 4 elems/thread
// ---------------------------------------------------------------------------
__global__ __launch_bounds__(256) void cvt_f16(
    const float* __restrict__ src, _Float16* __restrict__ dst)
{
    int i = blockIdx.x * 256 + threadIdx.x;
    float4 v = *(const float4*)&src[i * 4];
    f16x4 o;
    o[0] = (_Float16)v.x; o[1] = (_Float16)v.y;
    o[2] = (_Float16)v.z; o[3] = (_Float16)v.w;
    *(f16x4*)&dst[i * 4] = o;
}

// ---------------------------------------------------------------------------
// RoPE cos/sin table: tab[s][i] = {cos(s*invfreq_i), sin(s*invfreq_i)}, i<32
// ---------------------------------------------------------------------------
__global__ __launch_bounds__(256) void rope_tab_k(float2* __restrict__ tab)
{
    int idx = blockIdx.x * 256 + threadIdx.x;   // 0..65535
    int s = idx >> 5, i = idx & 31;
    float inv = expf(-(float)i * 0.2878231366242553f);   // 10000^(-i/32)
    float ang = (float)s * inv;
    tab[idx] = make_float2(cosf(ang), sinf(ang));
}

// ---------------------------------------------------------------------------
// W [K][N] f32 -> WT [N][K] fp16  (32x32 tiles)
// ---------------------------------------------------------------------------
__global__ __launch_bounds__(256) void transpose_cvt(
    const float* __restrict__ W, _Float16* __restrict__ T, int K, int N)
{
    __shared__ float t[32][33];
    const int tx = threadIdx.x & 31;
    const int ty = threadIdx.x >> 5;          // 0..7
    const int n0 = blockIdx.x * 32, k0 = blockIdx.y * 32;

    #pragma unroll
    for (int i = 0; i < 4; ++i)
        t[ty + i * 8][tx] = W[(size_t)(k0 + ty + i * 8) * N + n0 + tx];
    __syncthreads();
    #pragma unroll
    for (int i = 0; i < 4; ++i) {
        int n = n0 + ty + i * 8;
        T[(size_t)n * K + k0 + tx] = (_Float16)t[tx][ty + i * 8];
    }
}

// ---------------------------------------------------------------------------
// GEMM1 fused: xh[2048][1024]f16 @ WqkvT[3072][1024]f16 -> RoPE + scatter.
// 128x128 tile, BK=64, 4 waves (2x2), wave tile 64x64 => 32 MFMA/barrier-pair.
// LDS rows 128B, granule swizzle gr^(row&7): even bank spread for staging
// writes and fragment reads.  Epilogue: each wave's 64-col span = 1 head;
// rope pairs (hd, hd+32) = acc cols j and j+2 (same thread).
// q -> f32 [h][s][64]; k -> rope + bf16 hi/lo split; v -> bf16 [s][1024].
// ---------------------------------------------------------------------------
__global__ __launch_bounds__(256) void gemm1_fused(
    const _Float16* __restrict__ A, const _Float16* __restrict__ B,
    const float2* __restrict__ tab,
    float* __restrict__ qb, unsigned short* __restrict__ khb,
    unsigned short* __restrict__ klb, unsigned short* __restrict__ vbf)
{
    constexpr int K = DMODEL;
    __shared__ _Float16 As[128 * 64];
    __shared__ _Float16 Bs[128 * 64];

    const int tid = threadIdx.x;
    const int w = tid >> 6, lane = tid & 63;
    const int m16 = lane & 15, g = lane >> 4;
    const int wr = w >> 1, wc = w & 1;
    const int bm = blockIdx.y * 128, bn = blockIdx.x * 128;

    f32x4 acc[4][4];
    #pragma unroll
    for (int i = 0; i < 4; ++i)
        #pragma unroll
        for (int j = 0; j < 4; ++j) acc[i][j] = (f32x4)(0.0f);

    uint4 ra[4], rb[4];
    #pragma unroll
    for (int p = 0; p < 4; ++p) {
        int f = p * 256 + tid, row = f >> 3, gr = f & 7;
        ra[p] = *(const uint4*)&A[(size_t)(bm + row) * K + gr * 8];
        rb[p] = *(const uint4*)&B[(size_t)(bn + row) * K + gr * 8];
    }

    for (int kt = 0; kt < 16; ++kt) {
        __syncthreads();
        #pragma unroll
        for (int p = 0; p < 4; ++p) {
            int f = p * 256 + tid, row = f >> 3, gr = f & 7;
            int slot = (gr ^ (row & 7)) << 3;
            *(uint4*)&As[row * 64 + slot] = ra[p];
            *(uint4*)&Bs[row * 64 + slot] = rb[p];
        }
        __syncthreads();

        if (kt < 15) {
            int k0 = (kt + 1) * 64;
            #pragma unroll
            for (int p = 0; p < 4; ++p) {
                int f = p * 256 + tid, row = f >> 3, gr = f & 7;
                ra[p] = *(const uint4*)&A[(size_t)(bm + row) * K + k0 + gr * 8];
                rb[p] = *(const uint4*)&B[(size_t)(bn + row) * K + k0 + gr * 8];
            }
        }

        #pragma unroll
        for (int kh = 0; kh < 2; ++kh) {
            f16x8 af[4], bf_[4];
            #pragma unroll
            for (int i = 0; i < 4; ++i) {
                int row = wr * 64 + i * 16 + m16;
                af[i] = *(const f16x8*)&As[row * 64 + (((kh * 4 + g) ^ (row & 7)) << 3)];
            }
            #pragma unroll
            for (int j = 0; j < 4; ++j) {
                int row = wc * 64 + j * 16 + m16;
                bf_[j] = *(const f16x8*)&Bs[row * 64 + (((kh * 4 + g) ^ (row & 7)) << 3)];
            }
            #pragma unroll
            for (int j = 0; j < 4; ++j)
                #pragma unroll
                for (int i = 0; i < 4; ++i)
                    acc[i][j] = __builtin_amdgcn_mfma_f32_16x16x32_f16(
                        af[i], bf_[j], acc[i][j], 0, 0, 0);
        }
    }

    // ---- fused epilogue: u = 64-col unit = head slot ----
    const int u = blockIdx.x * 2 + wc;        // 0..47
    const int sbase = bm + wr * 64;
    if (u < 32) {
        const int h = (u < 16) ? u : u - 16;
        #pragma unroll
        for (int j = 0; j < 2; ++j) {
            const int hd_lo = j * 16 + m16;   // < 32
            #pragma unroll
            for (int i = 0; i < 4; ++i)
                #pragma unroll
                for (int r = 0; r < 4; ++r) {
                    int s = sbase + i * 16 + 4 * g + r;
                    float2 cs = tab[s * 32 + hd_lo];
                    float vlo = acc[i][j][r], vhi = acc[i][j + 2][r];
                    float rlo = vlo * cs.x - vhi * cs.y;
                    float rhi = vhi * cs.x + vlo * cs.y;
                    size_t o = ((size_t)h * S_LEN + s) * HDIM + hd_lo;
                    if (u < 16) {
                        qb[o] = rlo;
                        qb[o + 32] = rhi;
                    } else {
                        unsigned short hb = f2bf(rlo);
                        khb[o] = hb; klb[o] = f2bf(rlo - bf2f(hb));
                        hb = f2bf(rhi);
                        khb[o + 32] = hb; klb[o + 32] = f2bf(rhi - bf2f(hb));
                    }
                }
        }
    } else {
        const int hv = u - 32;
        #pragma unroll
        for (int j = 0; j < 4; ++j)
            #pragma unroll
            for (int i = 0; i < 4; ++i)
                #pragma unroll
                for (int r = 0; r < 4; ++r) {
                    int s = sbase + i * 16 + 4 * g + r;
                    vbf[(size_t)s * DMODEL + hv * HDIM + j * 16 + m16] =
                        f2bf(acc[i][j][r]);
                }
    }
}

// ---------------------------------------------------------------------------
// GEMM2: ah[2048][1024]f16 @ WoutT[1024][1024]f16 + x -> res f32.
// 128x64 tile, BK=64, 4 waves (2x2), wave tile 64x32.  256 blocks.
// ---------------------------------------------------------------------------
__global__ __launch_bounds__(256) void gemm2_k(
    const _Float16* __restrict__ A, const _Float16* __restrict__ B,
    const float* __restrict__ resid, float* __restrict__ C)
{
    constexpr int K = DMODEL;
    __shared__ _Float16 As[128 * 64];
    __shared__ _Float16 Bs[64 * 64];

    const int tid = threadIdx.x;
    const int w = tid >> 6, lane = tid & 63;
    const int m16 = lane & 15, g = lane >> 4;
    const int wr = w >> 1, wc = w & 1;
    const int bm = blockIdx.y * 128, bn = blockIdx.x * 64;

    f32x4 acc[4][2];
    #pragma unroll
    for (int i = 0; i < 4; ++i)
        #pragma unroll
        for (int j = 0; j < 2; ++j) acc[i][j] = (f32x4)(0.0f);

    uint4 ra[4], rb[2];
    #pragma unroll
    for (int p = 0; p < 4; ++p) {
        int f = p * 256 + tid, row = f >> 3, gr = f & 7;
        ra[p] = *(const uint4*)&A[(size_t)(bm + row) * K + gr * 8];
    }
    #pragma unroll
    for (int p = 0; p < 2; ++p) {
        int f = p * 256 + tid, row = f >> 3, gr = f & 7;
        rb[p] = *(const uint4*)&B[(size_t)(bn + row) * K + gr * 8];
    }

    for (int kt = 0; kt < 16; ++kt) {
        __syncthreads();
        #pragma unroll
        for (int p = 0; p < 4; ++p) {
            int f = p * 256 + tid, row = f >> 3, gr = f & 7;
            *(uint4*)&As[row * 64 + ((gr ^ (row & 7)) << 3)] = ra[p];
        }
        #pragma unroll
        for (int p = 0; p < 2; ++p) {
            int f = p * 256 + tid, row = f >> 3, gr = f & 7;
            *(uint4*)&Bs[row * 64 + ((gr ^ (row & 7)) << 3)] = rb[p];
        }
        __syncthreads();

        if (kt < 15) {
            int k0 = (kt + 1) * 64;
            #pragma unroll
            for (int p = 0; p < 4; ++p) {
                int f = p * 256 + tid, row = f >> 3, gr = f & 7;
                ra[p] = *(const uint4*)&A[(size_t)(bm + row) * K + k0 + gr * 8];
            }
            #pragma unroll
            for (int p = 0; p < 2; ++p) {
                int f = p * 256 + tid, row = f >> 3, gr = f & 7;
                rb[p] = *(const uint4*)&B[(size_t)(bn + row) * K + k0 + gr * 8];
            }
        }

        #pragma unroll
        for (int kh = 0; kh < 2; ++kh) {
            f16x8 af[4], bf_[2];
            #pragma unroll
            for (int i = 0; i < 4; ++i) {
                int row = wr * 64 + i * 16 + m16;
                af[i] = *(const f16x8*)&As[row * 64 + (((kh * 4 + g) ^ (row & 7)) << 3)];
            }
            #pragma unroll
            for (int j = 0; j < 2; ++j) {
                int row = wc * 32 + j * 16 + m16;
                bf_[j] = *(const f16x8*)&Bs[row * 64 + (((kh * 4 + g) ^ (row & 7)) << 3)];
            }
            #pragma unroll
            for (int j = 0; j < 2; ++j)
                #pragma unroll
                for (int i = 0; i < 4; ++i)
                    acc[i][j] = __builtin_amdgcn_mfma_f32_16x16x32_f16(
                        af[i], bf_[j], acc[i][j], 0, 0, 0);
        }
    }

    const int g4 = g * 4;
    #pragma unroll
    for (int i = 0; i < 4; ++i)
        #pragma unroll
        for (int j = 0; j < 2; ++j) {
            int col = bn + wc * 32 + j * 16 + m16;
            #pragma unroll
            for (int r = 0; r < 4; ++r) {
                int row = bm + wr * 64 + i * 16 + g4 + r;
                C[(size_t)row * DMODEL + col] =
                    acc[i][j][r] + resid[(size_t)row * DMODEL + col];
            }
        }
}

// ---------------------------------------------------------------------------
// V transpose: vbf [s][h*64+d] bf16 -> vT [h][d][s] bf16
// ---------------------------------------------------------------------------
__global__ __launch_bounds__(256) void v_transpose(
    const unsigned short* __restrict__ vbf, unsigned short* __restrict__ vT)
{
    __shared__ unsigned short t[64][72];
    const int s0 = blockIdx.x * 64;
    const int h  = blockIdx.y;
    const int tid = threadIdx.x;
    const int dq  = (tid & 15) * 4;
    const int sl0 = tid >> 4;

    #pragma unroll
    for (int p = 0; p < 4; ++p) {
        int sl = sl0 + p * 16;
        ushort4 v = *(const ushort4*)&vbf[(size_t)(s0 + sl) * DMODEL + h * HDIM + dq];
        t[sl][dq] = v.x; t[sl][dq + 1] = v.y; t[sl][dq + 2] = v.z; t[sl][dq + 3] = v.w;
    }
    __syncthreads();
    #pragma unroll
    for (int p = 0; p < 2; ++p) {
        int u = tid + p * 256;
        int d = u >> 3, sb = (u & 7) * 8;
        s16x8 o;
        #pragma unroll
        for (int i = 0; i < 8; ++i) o[i] = (short)t[sb + i][d];
        *(s16x8*)&vT[((size_t)h * HDIM + d) * S_LEN + s0 + sb] = o;
    }
}

// ---------------------------------------------------------------------------
// MFMA flash-style windowed attention (validated rounds 4/6, unchanged).
// ---------------------------------------------------------------------------
#define KP 72
__global__ __launch_bounds__(256, 3) void attn_mfma(
    const float* __restrict__ qg, const unsigned short* __restrict__ khg,
    const unsigned short* __restrict__ klg, const unsigned short* __restrict__ vTg,
    _Float16* __restrict__ oh)
{
    __shared__ __align__(16) unsigned short Kh[64][KP], Kl[64][KP], Vt[64][KP];
    __shared__ __align__(16) unsigned short Pw[4][16][40];

    const int h   = blockIdx.y;
    const int s0  = blockIdx.x * 64;
    const int tid = threadIdx.x;
    const int w   = tid >> 6, lane = tid & 63;
    const int m16 = lane & 15, g = lane >> 4;
    const int t_base = s0 - 256;

    const int qrow = s0 + w * 16 + m16;
    const float* qp = qg + ((size_t)h * S_LEN + qrow) * HDIM;
    s16x8 qh[2], ql[2];
    #pragma unroll
    for (int c = 0; c < 2; ++c) {
        float4 f0 = *(const float4*)&qp[c * 32 + g * 8];
        float4 f1 = *(const float4*)&qp[c * 32 + g * 8 + 4];
        float f[8] = {f0.x, f0.y, f0.z, f0.w, f1.x, f1.y, f1.z, f1.w};
        #pragma unroll
        for (int j = 0; j < 8; ++j) {
            float v = f[j] * 0.125f;
            unsigned short hb = f2bf(v);
            qh[c][j] = (short)hb;
            ql[c][j] = (short)f2bf(v - bf2f(hb));
        }
    }

    const int qb_ = w * 16 + m16;
    int lo_b = 256 - s0; if (lo_b < qb_) lo_b = qb_;
    const int hi_b = qb_ + 256;

    f32x4 O[4];
    #pragma unroll
    for (int nt = 0; nt < 4; ++nt) O[nt] = (f32x4)(0.0f);
    float l_r[4] = {0.0f, 0.0f, 0.0f, 0.0f};
    float m_col = -1e30f;

    const int stage_min = (s0 >= 256) ? 0 : ((193 - s0 + 63) >> 6);

    for (int st = stage_min; st < 5; ++st) {
        __syncthreads();
        const int t0s = t_base + st * 64;
        #pragma unroll
        for (int pp = 0; pp < 2; ++pp) {
            int u = tid + pp * 256;
            int row = u >> 3, cb = (u & 7) * 8;
            int t = t0s + row;
            s16x8 vh = {}, vl = {};
            if (t >= 0) {
                size_t base = ((size_t)h * S_LEN + t) * HDIM + cb;
                vh = *(const s16x8*)&khg[base];
                vl = *(const s16x8*)&klg[base];
            }
            *(s16x8*)&Kh[row][cb] = vh;
            *(s16x8*)&Kl[row][cb] = vl;
        }
        #pragma unroll
        for (int pp = 0; pp < 2; ++pp) {
            int u = tid + pp * 256;
            int d = u >> 3, kb = (u & 7) * 8;
            int t = t0s + kb;
            s16x8 vv = {};
            if (t >= 0)
                vv = *(const s16x8*)&vTg[((size_t)h * HDIM + d) * S_LEN + t];
            *(s16x8*)&Vt[d][kb] = vv;
        }
        __syncthreads();

        #pragma unroll
        for (int ch = 0; ch < 2; ++ch) {
            f32x4 sc[2];
            #pragma unroll
            for (int kt2 = 0; kt2 < 2; ++kt2) {
                int krow = ch * 32 + kt2 * 16 + m16;
                s16x8 kh0 = *(const s16x8*)&Kh[krow][g * 8];
                s16x8 kh1 = *(const s16x8*)&Kh[krow][32 + g * 8];
                s16x8 kl0 = *(const s16x8*)&Kl[krow][g * 8];
                s16x8 kl1 = *(const s16x8*)&Kl[krow][32 + g * 8];
                f32x4 a = (f32x4)(0.0f);
                a = __builtin_amdgcn_mfma_f32_16x16x32_bf16(kh0, qh[0], a, 0, 0, 0);
                a = __builtin_amdgcn_mfma_f32_16x16x32_bf16(kh1, qh[1], a, 0, 0, 0);
                a = __builtin_amdgcn_mfma_f32_16x16x32_bf16(kh0, ql[0], a, 0, 0, 0);
                a = __builtin_amdgcn_mfma_f32_16x16x32_bf16(kh1, ql[1], a, 0, 0, 0);
                a = __builtin_amdgcn_mfma_f32_16x16x32_bf16(kl0, qh[0], a, 0, 0, 0);
                a = __builtin_amdgcn_mfma_f32_16x16x32_bf16(kl1, qh[1], a, 0, 0, 0);
                sc[kt2] = a;
            }

            float scm[8];
            float pmax = -1e30f;
            #pragma unroll
            for (int kt2 = 0; kt2 < 2; ++kt2)
                #pragma unroll
                for (int r = 0; r < 4; ++r) {
                    int ki = st * 64 + ch * 32 + kt2 * 16 + 4 * g + r;
                    bool vd = (ki >= lo_b) && (ki <= hi_b);
                    float s_ = vd ? sc[kt2][r] : -1e30f;
                    scm[kt2 * 4 + r] = s_;
                    pmax = fmaxf(pmax, s_);
                }
            pmax = fmaxf(pmax, __shfl_xor(pmax, 16));
            pmax = fmaxf(pmax, __shfl_xor(pmax, 32));
            float mnew = fmaxf(m_col, pmax);

            float p[8];
            float psum = 0.0f;
            #pragma unroll
            for (int i = 0; i < 8; ++i) {
                float e = (scm[i] > -9e29f) ? __expf(scm[i] - mnew) : 0.0f;
                p[i] = e;
                psum += e;
            }
            psum += __shfl_xor(psum, 16);
            psum += __shfl_xor(psum, 32);
            float scale = __expf(m_col - mnew);
            m_col = mnew;

            #pragma unroll
            for (int r = 0; r < 4; ++r) {
                float sr = __shfl(scale, 4 * g + r);
                float ps = __shfl(psum, 4 * g + r);
                l_r[r] = l_r[r] * sr + ps;
                O[0][r] *= sr; O[1][r] *= sr; O[2][r] *= sr; O[3][r] *= sr;
            }

            unsigned int d0, d1, d2, d3;
            asm("v_cvt_pk_bf16_f32 %0, %1, %2" : "=v"(d0) : "v"(p[0]), "v"(p[1]));
            asm("v_cvt_pk_bf16_f32 %0, %1, %2" : "=v"(d1) : "v"(p[2]), "v"(p[3]));
            asm("v_cvt_pk_bf16_f32 %0, %1, %2" : "=v"(d2) : "v"(p[4]), "v"(p[5]));
            asm("v_cvt_pk_bf16_f32 %0, %1, %2" : "=v"(d3) : "v"(p[6]), "v"(p[7]));
            *(uint2*)&Pw[w][m16][4 * g]      = make_uint2(d0, d1);
            *(uint2*)&Pw[w][m16][16 + 4 * g] = make_uint2(d2, d3);
            asm volatile("s_waitcnt lgkmcnt(0)" ::: "memory");
            __builtin_amdgcn_sched_barrier(0);
            s16x8 pa = *(const s16x8*)&Pw[w][m16][g * 8];

            #pragma unroll
            for (int nt = 0; nt < 4; ++nt) {
                s16x8 vb = *(const s16x8*)&Vt[nt * 16 + m16][ch * 32 + g * 8];
                O[nt] = __builtin_amdgcn_mfma_f32_16x16x32_bf16(pa, vb, O[nt], 0, 0, 0);
            }
        }
    }

    #pragma unroll
    for (int r = 0; r < 4; ++r) {
        float linv = 1.0f / l_r[r];
        int srow = s0 + w * 16 + 4 * g + r;
        size_t obase = (size_t)srow * DMODEL + h * HDIM;
        #pragma unroll
        for (int nt = 0; nt < 4; ++nt)
            oh[obase + nt * 16 + m16] = (_Float16)(O[nt][r] * linv);
    }
}

// ---------------------------------------------------------------------------
// LayerNorm, one block per row of 1024
// ---------------------------------------------------------------------------
__global__ __launch_bounds__(256) void layernorm_k(
    const float* __restrict__ res, const float* __restrict__ gamma,
    const float* __restrict__ beta, float* __restrict__ y)
{
    const int row  = blockIdx.x;
    const int tid  = threadIdx.x;
    const int wave = tid >> 6;
    const int lane = tid & 63;
    const float* r = res + (size_t)row * DMODEL;

    float4 xv = *(const float4*)&r[tid * 4];
    float ssum = xv.x + xv.y + xv.z + xv.w;
    float ssq  = xv.x * xv.x + xv.y * xv.y + xv.z * xv.z + xv.w * xv.w;

    #pragma unroll
    for (int off = 1; off < 64; off <<= 1) {
        ssum += __shfl_xor(ssum, off);
        ssq  += __shfl_xor(ssq, off);
    }

    __shared__ float wsum[4], wsq[4];
    if (lane == 0) { wsum[wave] = ssum; wsq[wave] = ssq; }
    __syncthreads();

    float tot  = wsum[0] + wsum[1] + wsum[2] + wsum[3];
    float tot2 = wsq[0] + wsq[1] + wsq[2] + wsq[3];
    float mu   = tot * (1.0f / DMODEL);
    float var  = tot2 * (1.0f / DMODEL) - mu * mu;
    float rstd = rsqrtf(var + 1e-5f);

    float4 gm = *(const float4*)&gamma[tid * 4];
    float4 be = *(const float4*)&beta[tid * 4];
    float4 yo;
    yo.x = (xv.x - mu) * rstd * gm.x + be.x;
    yo.y = (xv.y - mu) * rstd * gm.y + be.y;
    yo.z = (xv.z - mu) * rstd * gm.z + be.z;
    yo.w = (xv.w - mu) * rstd * gm.w + be.w;
    *(float4*)&y[(size_t)row * DMODEL + tid * 4] = yo;
}

// ---------------------------------------------------------------------------
extern "C" void kernel_launch(void* const* d_in, const int* in_sizes, int n_in,
                              void* d_out, int out_size, void* d_ws, size_t ws_size,
                              hipStream_t stream) {
    const float* x     = (const float*)d_in[0];
    const float* state = (const float*)d_in[1];
    const float* Wqkv  = (const float*)d_in[2];
    const float* Wout  = (const float*)d_in[3];
    const float* gamma = (const float*)d_in[4];
    const float* beta  = (const float*)d_in[5];
    float* out = (float*)d_out;

    char* base = (char*)d_ws;
    _Float16*       ah    = (_Float16*)(base + 0);              // [2048][1024] f16
    float*          res   = (float*)(base + 4194304);           // [2048][1024] f32
    float*          qb    = (float*)(base + 12582912);          // [16][2048][64] f32
    unsigned short* khb   = (unsigned short*)(base + 20971520); // [16][2048][64] bf16
    unsigned short* klb   = (unsigned short*)(base + 25165824);
    unsigned short* vbf   = (unsigned short*)(base + 29360128); // [2048][1024] bf16
    unsigned short* vT    = (unsigned short*)(base + 33554432); // [16][64][2048] bf16
    _Float16*       WqkvT = (_Float16*)(base + 37748736);       // [3072][1024] f16
    _Float16*       WoutT = (_Float16*)(base + 44040192);       // [1024][1024] f16
    _Float16*       xh    = (_Float16*)(base + 46137344);       // [2048][1024] f16
    float2*         tab   = (float2*)(base + 50331648);         // [2048][32]

    // --- prep ---
    cvt_f16<<<(S_LEN * DMODEL) / 1024, 256, 0, stream>>>(x, xh);
    rope_tab_k<<<(S_LEN * 32) / 256, 256, 0, stream>>>(tab);
    transpose_cvt<<<dim3(N_QKV / 32, DMODEL / 32), 256, 0, stream>>>(
        Wqkv, WqkvT, DMODEL, N_QKV);
    transpose_cvt<<<dim3(DMODEL / 32, DMODEL / 32), 256, 0, stream>>>(
        Wout, WoutT, DMODEL, DMODEL);

    // --- QKV projection + fused RoPE/scatter: 384 blocks ---
    gemm1_fused<<<dim3(N_QKV / 128, S_LEN / 128), 256, 0, stream>>>(
        xh, WqkvT, tab, qb, khb, klb, vbf);

    // --- V transpose to [h][d][s] bf16 ---
    v_transpose<<<dim3(S_LEN / 64, NHEADS), 256, 0, stream>>>(vbf, vT);

    // --- MFMA windowed attention ---
    attn_mfma<<<dim3(S_LEN / 64, NHEADS), 256, 0, stream>>>(
        qb, khb, klb, vT, ah);

    // --- out projection + residual: 256 blocks ---
    gemm2_k<<<dim3(DMODEL / 64, S_LEN / 128), 256, 0, stream>>>(
        ah, WoutT, x, res);

    // --- LayerNorm ---
    layernorm_k<<<S_LEN, 256, 0, stream>>>(res, gamma, beta, out);

    // --- state passthrough ---
    hipMemcpyAsync(out + (size_t)S_LEN * DMODEL, state,
                   (size_t)DMODEL * sizeof(float),
                   hipMemcpyDeviceToDevice, stream);
}

// Round 9
// 161.579 us; speedup vs baseline: 1.5673x; 1.5673x over previous
//
#include <hip/hip_runtime.h>
#include <math.h>

#define S_LEN 2048
#define DMODEL 1024
#define NHEADS 16
#define HDIM 64
#define WIN 256
#define N_QKV 3072

typedef __attribute__((ext_vector_type(8))) short s16x8;
typedef __attribute__((ext_vector_type(8))) _Float16 f16x8;
typedef __attribute__((ext_vector_type(4))) _Float16 f16x4;
typedef __attribute__((ext_vector_type(4))) float f32x4;

typedef __attribute__((address_space(1))) const void gas_void;
typedef __attribute__((address_space(3))) void las_void;

__device__ inline unsigned short f2bf(float f) {
    unsigned int u = __float_as_uint(f);
    u += 0x7FFFu + ((u >> 16) & 1u);      // round-to-nearest-even
    return (unsigned short)(u >> 16);
}
__device__ inline float bf2f(unsigned short h) {
    return __uint_as_float(((unsigned int)h) << 16);
}

// ---------------------------------------------------------------------------
// fp32 -> fp16 convert, 4 elems/thread
// ---------------------------------------------------------------------------
__global__ __launch_bounds__(256) void cvt_f16(
    const float* __restrict__ src, _Float16* __restrict__ dst)
{
    int i = blockIdx.x * 256 + threadIdx.x;
    float4 v = *(const float4*)&src[i * 4];
    f16x4 o;
    o[0] = (_Float16)v.x; o[1] = (_Float16)v.y;
    o[2] = (_Float16)v.z; o[3] = (_Float16)v.w;
    *(f16x4*)&dst[i * 4] = o;
}

// ---------------------------------------------------------------------------
// RoPE cos/sin table: tab[s][i] = {cos(s*invfreq_i), sin(s*invfreq_i)}, i<32
// ---------------------------------------------------------------------------
__global__ __launch_bounds__(256) void rope_tab_k(float2* __restrict__ tab)
{
    int idx = blockIdx.x * 256 + threadIdx.x;   // 0..65535
    int s = idx >> 5, i = idx & 31;
    float inv = expf(-(float)i * 0.2878231366242553f);   // 10000^(-i/32)
    float ang = (float)s * inv;
    tab[idx] = make_float2(cosf(ang), sinf(ang));
}

// ---------------------------------------------------------------------------
// W [K][N] f32 -> WT [N][K] fp16  (32x32 tiles)
// ---------------------------------------------------------------------------
__global__ __launch_bounds__(256) void transpose_cvt(
    const float* __restrict__ W, _Float16* __restrict__ T, int K, int N)
{
    __shared__ float t[32][33];
    const int tx = threadIdx.x & 31;
    const int ty = threadIdx.x >> 5;          // 0..7
    const int n0 = blockIdx.x * 32, k0 = blockIdx.y * 32;

    #pragma unroll
    for (int i = 0; i < 4; ++i)
        t[ty + i * 8][tx] = W[(size_t)(k0 + ty + i * 8) * N + n0 + tx];
    __syncthreads();
    #pragma unroll
    for (int i = 0; i < 4; ++i) {
        int n = n0 + ty + i * 8;
        T[(size_t)n * K + k0 + tx] = (_Float16)t[tx][ty + i * 8];
    }
}

// ---------------------------------------------------------------------------
// m97-structure fp16 GEMM with global_load_lds staging (HW-verified recipe).
// C[M,N] = A[M,K]@B[K,N] (+resid); A [M][K] f16, B = B^T [N][K] f16.
// BK=32 (64B rows), LDS linear (required by gload_lds), source-granule
// swizzle gran^(row&3) cuts stride-64B read conflicts from 8-way to 4-way.
// 4 waves 2x2, wave tile (BM/2)x(BN/2), 16 MFMA per barrier-pair at 128^2.
// ---------------------------------------------------------------------------
template<int BM, int BN, bool RES>
__global__ __launch_bounds__(256) void gemm_lds(
    const _Float16* __restrict__ A, const _Float16* __restrict__ B,
    const float* __restrict__ resid, float* __restrict__ C,
    int M, int N, int K)
{
    constexpr int WM = BM / 2, WN = BN / 2;
    constexpr int MI = WM / 16, NJ = WN / 16;

    __shared__ _Float16 As[BM * 32];
    __shared__ _Float16 Bs[BN * 32];

    const int tid = threadIdx.x;
    const int w = tid >> 6, lane = tid & 63;
    const int m16 = lane & 15, g = lane >> 4;
    const int wr = w >> 1, wc = w & 1;
    const int bm = blockIdx.y * BM, bn = blockIdx.x * BN;

    // staging coords: lane covers (row = lane>>2) within a 16-row chunk,
    // source granule swizzled so LDS stays linear but banks spread on read.
    const int srow = lane >> 2;
    const int sgran = (lane & 3) ^ (srow & 3);

    f32x4 acc[MI][NJ];
    #pragma unroll
    for (int i = 0; i < MI; ++i)
        #pragma unroll
        for (int j = 0; j < NJ; ++j) acc[i][j] = (f32x4)(0.0f);

    for (int kt = 0; kt < K / 32; ++kt) {
        const int k0 = kt * 32;
        __syncthreads();          // prior reads done; LDS safe to overwrite
        #pragma unroll
        for (int p = 0; p < BM / 64; ++p) {
            int row = p * 64 + w * 16 + srow;
            __builtin_amdgcn_global_load_lds(
                (gas_void*)&A[(size_t)(bm + row) * K + k0 + sgran * 8],
                (las_void*)&As[(p * 64 + w * 16) * 32], 16, 0, 0);
        }
        #pragma unroll
        for (int p = 0; p < BN / 64; ++p) {
            int row = p * 64 + w * 16 + srow;
            __builtin_amdgcn_global_load_lds(
                (gas_void*)&B[(size_t)(bn + row) * K + k0 + sgran * 8],
                (las_void*)&Bs[(p * 64 + w * 16) * 32], 16, 0, 0);
        }
        __syncthreads();          // compiler drains vmcnt before barrier

        f16x8 af[MI], bf_[NJ];
        #pragma unroll
        for (int i = 0; i < MI; ++i) {
            int row = wr * WM + i * 16 + m16;
            af[i] = *(const f16x8*)&As[row * 32 + ((g ^ (row & 3)) << 3)];
        }
        #pragma unroll
        for (int j = 0; j < NJ; ++j) {
            int row = wc * WN + j * 16 + m16;
            bf_[j] = *(const f16x8*)&Bs[row * 32 + ((g ^ (row & 3)) << 3)];
        }
        #pragma unroll
        for (int j = 0; j < NJ; ++j)
            #pragma unroll
            for (int i = 0; i < MI; ++i)
                acc[i][j] = __builtin_amdgcn_mfma_f32_16x16x32_f16(
                    af[i], bf_[j], acc[i][j], 0, 0, 0);
    }

    // epilogue: C/D map col = lane&15, row = 4*(lane>>4)+reg (HW-verified)
    const int g4 = g * 4;
    #pragma unroll
    for (int i = 0; i < MI; ++i)
        #pragma unroll
        for (int j = 0; j < NJ; ++j) {
            int col = bn + wc * WN + j * 16 + m16;
            #pragma unroll
            for (int r = 0; r < 4; ++r) {
                int row = bm + wr * WM + i * 16 + g4 + r;
                float val = acc[i][j][r];
                if (RES) val += resid[(size_t)row * N + col];
                C[(size_t)row * N + col] = val;
            }
        }
}

// ---------------------------------------------------------------------------
// RoPE + scatter: qkv[s][3072] f32 -> q f16 (pre-scaled 1/8) and k f16,
// both [h][s][64].
// ---------------------------------------------------------------------------
__global__ __launch_bounds__(256) void rope_scatter(
    const float* __restrict__ qkv, const float2* __restrict__ tab,
    _Float16* __restrict__ qf, _Float16* __restrict__ kf)
{
    int idx = blockIdx.x * 256 + threadIdx.x;   // 0 .. S*D-1
    int s  = idx >> 10;
    int r  = idx & 1023;
    int hd = r & 63;
    int h  = r >> 6;
    const float* row = qkv + (size_t)s * N_QKV;

    float qv = row[r];
    float kv = row[DMODEL + r];

    float2 cs = tab[s * 32 + (hd & 31)];
    int   pr  = (hd < 32) ? r + 32 : r - 32;
    float sgn = (hd < 32) ? -1.0f : 1.0f;

    float qo = (qv * cs.x + sgn * row[pr] * cs.y) * 0.125f;
    float ko =  kv * cs.x + sgn * row[DMODEL + pr] * cs.y;

    size_t o = ((size_t)h * S_LEN + s) * HDIM + hd;
    qf[o] = (_Float16)qo;
    kf[o] = (_Float16)ko;
}

// ---------------------------------------------------------------------------
// V transpose: qkv v-part [s][h*64+d] f32 -> vT [h][d][s] bf16
// ---------------------------------------------------------------------------
__global__ __launch_bounds__(256) void v_transpose(
    const float* __restrict__ qkv, unsigned short* __restrict__ vT)
{
    __shared__ float t[64][65];
    const int s0 = blockIdx.x * 64;
    const int h  = blockIdx.y;
    const int tid = threadIdx.x;
    const int dq  = (tid & 15) * 4;
    const int sl0 = tid >> 4;

    #pragma unroll
    for (int p = 0; p < 4; ++p) {
        int sl = sl0 + p * 16;
        float4 v = *(const float4*)&qkv[(size_t)(s0 + sl) * N_QKV + 2 * DMODEL + h * HDIM + dq];
        t[sl][dq] = v.x; t[sl][dq + 1] = v.y; t[sl][dq + 2] = v.z; t[sl][dq + 3] = v.w;
    }
    __syncthreads();
    #pragma unroll
    for (int p = 0; p < 2; ++p) {
        int u = tid + p * 256;
        int d = u >> 3, sb = (u & 7) * 8;
        s16x8 o;
        #pragma unroll
        for (int i = 0; i < 8; ++i) o[i] = (short)f2bf(t[sb + i][d]);
        *(s16x8*)&vT[((size_t)h * HDIM + d) * S_LEN + s0 + sb] = o;
    }
}

// ---------------------------------------------------------------------------
// MFMA flash-style windowed attention. f16 single-pass scores (2 MFMA per
// 16-key tile vs 6 for bf16x3); P,V bf16 as validated. Output f16.
// ---------------------------------------------------------------------------
#define KP 72
__global__ __launch_bounds__(256, 3) void attn_mfma(
    const _Float16* __restrict__ qg, const _Float16* __restrict__ kg,
    const unsigned short* __restrict__ vTg, _Float16* __restrict__ oh)
{
    __shared__ __align__(16) _Float16 Ks[64][KP];
    __shared__ __align__(16) unsigned short Vt[64][KP];
    __shared__ __align__(16) unsigned short Pw[4][16][40];

    const int h   = blockIdx.y;
    const int s0  = blockIdx.x * 64;
    const int tid = threadIdx.x;
    const int w   = tid >> 6, lane = tid & 63;
    const int m16 = lane & 15, g = lane >> 4;
    const int t_base = s0 - 256;

    // ---- Q fragments (already scaled 1/8 by rope_scatter) ----
    const int qrow = s0 + w * 16 + m16;
    const _Float16* qp = qg + ((size_t)h * S_LEN + qrow) * HDIM;
    f16x8 qf[2];
    qf[0] = *(const f16x8*)&qp[g * 8];
    qf[1] = *(const f16x8*)&qp[32 + g * 8];

    const int qb_ = w * 16 + m16;
    int lo_b = 256 - s0; if (lo_b < qb_) lo_b = qb_;
    const int hi_b = qb_ + 256;

    f32x4 O[4];
    #pragma unroll
    for (int nt = 0; nt < 4; ++nt) O[nt] = (f32x4)(0.0f);
    float l_r[4] = {0.0f, 0.0f, 0.0f, 0.0f};
    float m_col = -1e30f;

    const int stage_min = (s0 >= 256) ? 0 : ((193 - s0 + 63) >> 6);

    for (int st = stage_min; st < 5; ++st) {
        __syncthreads();
        const int t0s = t_base + st * 64;
        #pragma unroll
        for (int pp = 0; pp < 2; ++pp) {
            int u = tid + pp * 256;
            int row = u >> 3, cb = (u & 7) * 8;
            int t = t0s + row;
            f16x8 kv = {};
            if (t >= 0)
                kv = *(const f16x8*)&kg[((size_t)h * S_LEN + t) * HDIM + cb];
            *(f16x8*)&Ks[row][cb] = kv;
        }
        #pragma unroll
        for (int pp = 0; pp < 2; ++pp) {
            int u = tid + pp * 256;
            int d = u >> 3, kb = (u & 7) * 8;
            int t = t0s + kb;
            s16x8 vv = {};
            if (t >= 0)
                vv = *(const s16x8*)&vTg[((size_t)h * HDIM + d) * S_LEN + t];
            *(s16x8*)&Vt[d][kb] = vv;
        }
        __syncthreads();

        #pragma unroll
        for (int ch = 0; ch < 2; ++ch) {
            // ---- scores: f16 single-pass, 2 MFMA per 16-key tile ----
            f32x4 sc[2];
            #pragma unroll
            for (int kt2 = 0; kt2 < 2; ++kt2) {
                int krow = ch * 32 + kt2 * 16 + m16;
                f16x8 k0 = *(const f16x8*)&Ks[krow][g * 8];
                f16x8 k1 = *(const f16x8*)&Ks[krow][32 + g * 8];
                f32x4 a = (f32x4)(0.0f);
                a = __builtin_amdgcn_mfma_f32_16x16x32_f16(k0, qf[0], a, 0, 0, 0);
                a = __builtin_amdgcn_mfma_f32_16x16x32_f16(k1, qf[1], a, 0, 0, 0);
                sc[kt2] = a;
            }

            float scm[8];
            float pmax = -1e30f;
            #pragma unroll
            for (int kt2 = 0; kt2 < 2; ++kt2)
                #pragma unroll
                for (int r = 0; r < 4; ++r) {
                    int ki = st * 64 + ch * 32 + kt2 * 16 + 4 * g + r;
                    bool vd = (ki >= lo_b) && (ki <= hi_b);
                    float s_ = vd ? sc[kt2][r] : -1e30f;
                    scm[kt2 * 4 + r] = s_;
                    pmax = fmaxf(pmax, s_);
                }
            pmax = fmaxf(pmax, __shfl_xor(pmax, 16));
            pmax = fmaxf(pmax, __shfl_xor(pmax, 32));
            float mnew = fmaxf(m_col, pmax);

            float p[8];
            float psum = 0.0f;
            #pragma unroll
            for (int i = 0; i < 8; ++i) {
                float e = (scm[i] > -9e29f) ? __expf(scm[i] - mnew) : 0.0f;
                p[i] = e;
                psum += e;
            }
            psum += __shfl_xor(psum, 16);
            psum += __shfl_xor(psum, 32);
            float scale = __expf(m_col - mnew);
            m_col = mnew;

            #pragma unroll
            for (int r = 0; r < 4; ++r) {
                float sr = __shfl(scale, 4 * g + r);
                float ps = __shfl(psum, 4 * g + r);
                l_r[r] = l_r[r] * sr + ps;
                O[0][r] *= sr; O[1][r] *= sr; O[2][r] *= sr; O[3][r] *= sr;
            }

            unsigned int d0, d1, d2, d3;
            asm("v_cvt_pk_bf16_f32 %0, %1, %2" : "=v"(d0) : "v"(p[0]), "v"(p[1]));
            asm("v_cvt_pk_bf16_f32 %0, %1, %2" : "=v"(d1) : "v"(p[2]), "v"(p[3]));
            asm("v_cvt_pk_bf16_f32 %0, %1, %2" : "=v"(d2) : "v"(p[4]), "v"(p[5]));
            asm("v_cvt_pk_bf16_f32 %0, %1, %2" : "=v"(d3) : "v"(p[6]), "v"(p[7]));
            *(uint2*)&Pw[w][m16][4 * g]      = make_uint2(d0, d1);
            *(uint2*)&Pw[w][m16][16 + 4 * g] = make_uint2(d2, d3);
            asm volatile("s_waitcnt lgkmcnt(0)" ::: "memory");
            __builtin_amdgcn_sched_barrier(0);
            s16x8 pa = *(const s16x8*)&Pw[w][m16][g * 8];

            #pragma unroll
            for (int nt = 0; nt < 4; ++nt) {
                s16x8 vb = *(const s16x8*)&Vt[nt * 16 + m16][ch * 32 + g * 8];
                O[nt] = __builtin_amdgcn_mfma_f32_16x16x32_bf16(pa, vb, O[nt], 0, 0, 0);
            }
        }
    }

    #pragma unroll
    for (int r = 0; r < 4; ++r) {
        float linv = 1.0f / l_r[r];
        int srow = s0 + w * 16 + 4 * g + r;
        size_t obase = (size_t)srow * DMODEL + h * HDIM;
        #pragma unroll
        for (int nt = 0; nt < 4; ++nt)
            oh[obase + nt * 16 + m16] = (_Float16)(O[nt][r] * linv);
    }
}

// ---------------------------------------------------------------------------
// LayerNorm, one block per row of 1024
// ---------------------------------------------------------------------------
__global__ __launch_bounds__(256) void layernorm_k(
    const float* __restrict__ res, const float* __restrict__ gamma,
    const float* __restrict__ beta, float* __restrict__ y)
{
    const int row  = blockIdx.x;
    const int tid  = threadIdx.x;
    const int wave = tid >> 6;
    const int lane = tid & 63;
    const float* r = res + (size_t)row * DMODEL;

    float4 xv = *(const float4*)&r[tid * 4];
    float ssum = xv.x + xv.y + xv.z + xv.w;
    float ssq  = xv.x * xv.x + xv.y * xv.y + xv.z * xv.z + xv.w * xv.w;

    #pragma unroll
    for (int off = 1; off < 64; off <<= 1) {
        ssum += __shfl_xor(ssum, off);
        ssq  += __shfl_xor(ssq, off);
    }

    __shared__ float wsum[4], wsq[4];
    if (lane == 0) { wsum[wave] = ssum; wsq[wave] = ssq; }
    __syncthreads();

    float tot  = wsum[0] + wsum[1] + wsum[2] + wsum[3];
    float tot2 = wsq[0] + wsq[1] + wsq[2] + wsq[3];
    float mu   = tot * (1.0f / DMODEL);
    float var  = tot2 * (1.0f / DMODEL) - mu * mu;
    float rstd = rsqrtf(var + 1e-5f);

    float4 gm = *(const float4*)&gamma[tid * 4];
    float4 be = *(const float4*)&beta[tid * 4];
    float4 yo;
    yo.x = (xv.x - mu) * rstd * gm.x + be.x;
    yo.y = (xv.y - mu) * rstd * gm.y + be.y;
    yo.z = (xv.z - mu) * rstd * gm.z + be.z;
    yo.w = (xv.w - mu) * rstd * gm.w + be.w;
    *(float4*)&y[(size_t)row * DMODEL + tid * 4] = yo;
}

// ---------------------------------------------------------------------------
extern "C" void kernel_launch(void* const* d_in, const int* in_sizes, int n_in,
                              void* d_out, int out_size, void* d_ws, size_t ws_size,
                              hipStream_t stream) {
    const float* x     = (const float*)d_in[0];
    const float* state = (const float*)d_in[1];
    const float* Wqkv  = (const float*)d_in[2];
    const float* Wout  = (const float*)d_in[3];
    const float* gamma = (const float*)d_in[4];
    const float* beta  = (const float*)d_in[5];
    float* out = (float*)d_out;

    char* base = (char*)d_ws;
    // region A [0, 25.2MB): qkv_raw f32; later overlaid by ah (0..4MB) and
    // res (8..16MB) once attn starts (v_transpose is last qkv reader).
    float*     qkv_raw = (float*)base;                        // [2048][3072] f32
    _Float16*  ah      = (_Float16*)base;                     // [2048][1024] f16
    float*     res     = (float*)(base + 8388608);            // [2048][1024] f32
    _Float16*  qf      = (_Float16*)(base + 25165824);        // [16][2048][64] f16
    _Float16*  kf      = (_Float16*)(base + 29360128);        // [16][2048][64] f16
    unsigned short* vT = (unsigned short*)(base + 33554432);  // [16][64][2048] bf16
    _Float16*  WqkvT   = (_Float16*)(base + 37748736);        // [3072][1024] f16
    _Float16*  WoutT   = (_Float16*)(base + 44040192);        // [1024][1024] f16
    _Float16*  xh      = (_Float16*)(base + 46137344);        // [2048][1024] f16
    float2*    tab     = (float2*)(base + 50331648);          // [2048][32]

    // --- prep ---
    cvt_f16<<<(S_LEN * DMODEL) / 1024, 256, 0, stream>>>(x, xh);
    rope_tab_k<<<(S_LEN * 32) / 256, 256, 0, stream>>>(tab);
    transpose_cvt<<<dim3(N_QKV / 32, DMODEL / 32), 256, 0, stream>>>(
        Wqkv, WqkvT, DMODEL, N_QKV);
    transpose_cvt<<<dim3(DMODEL / 32, DMODEL / 32), 256, 0, stream>>>(
        Wout, WoutT, DMODEL, DMODEL);

    // --- QKV projection (m97 structure), dense row-major output ---
    gemm_lds<128, 128, false>
        <<<dim3(N_QKV / 128, S_LEN / 128), 256, 0, stream>>>(
            xh, WqkvT, nullptr, qkv_raw, S_LEN, N_QKV, DMODEL);

    // --- RoPE + scatter (q f16 pre-scaled, k f16) ---
    rope_scatter<<<(S_LEN * DMODEL) / 256, 256, 0, stream>>>(
        qkv_raw, tab, qf, kf);

    // --- V transpose to [h][d][s] bf16 ---
    v_transpose<<<dim3(S_LEN / 64, NHEADS), 256, 0, stream>>>(qkv_raw, vT);

    // --- MFMA windowed attention (f16 scores) ---
    attn_mfma<<<dim3(S_LEN / 64, NHEADS), 256, 0, stream>>>(qf, kf, vT, ah);

    // --- out projection + residual ---
    gemm_lds<64, 64, true>
        <<<dim3(DMODEL / 64, S_LEN / 64), 256, 0, stream>>>(
            ah, WoutT, x, res, S_LEN, DMODEL, DMODEL);

    // --- LayerNorm ---
    layernorm_k<<<S_LEN, 256, 0, stream>>>(res, gamma, beta, out);

    // --- state passthrough ---
    hipMemcpyAsync(out + (size_t)S_LEN * DMODEL, state,
                   (size_t)DMODEL * sizeof(float),
                   hipMemcpyDeviceToDevice, stream);
}

// Round 11
// 149.075 us; speedup vs baseline: 1.6987x; 1.0839x over previous
//
#include <hip/hip_runtime.h>
#include <math.h>

#define S_LEN 2048
#define DMODEL 1024
#define NHEADS 16
#define HDIM 64
#define WIN 256
#define N_QKV 3072

typedef __attribute__((ext_vector_type(8))) short s16x8;
typedef __attribute__((ext_vector_type(8))) _Float16 f16x8;
typedef __attribute__((ext_vector_type(4))) _Float16 f16x4;
typedef __attribute__((ext_vector_type(4))) float f32x4;

typedef __attribute__((address_space(1))) const void gas_void;
typedef __attribute__((address_space(3))) void las_void;

__device__ inline unsigned short f2bf(float f) {
    unsigned int u = __float_as_uint(f);
    u += 0x7FFFu + ((u >> 16) & 1u);      // round-to-nearest-even
    return (unsigned short)(u >> 16);
}
__device__ inline float bf2f(unsigned short h) {
    return __uint_as_float(((unsigned int)h) << 16);
}

// ---------------------------------------------------------------------------
// fp32 -> fp16 convert, 4 elems/thread
// ---------------------------------------------------------------------------
__global__ __launch_bounds__(256) void cvt_f16(
    const float* __restrict__ src, _Float16* __restrict__ dst)
{
    int i = blockIdx.x * 256 + threadIdx.x;
    float4 v = *(const float4*)&src[i * 4];
    f16x4 o;
    o[0] = (_Float16)v.x; o[1] = (_Float16)v.y;
    o[2] = (_Float16)v.z; o[3] = (_Float16)v.w;
    *(f16x4*)&dst[i * 4] = o;
}

// ---------------------------------------------------------------------------
// RoPE cos/sin table: tab[s][i] = {cos(s*invfreq_i), sin(s*invfreq_i)}, i<32
// ---------------------------------------------------------------------------
__global__ __launch_bounds__(256) void rope_tab_k(float2* __restrict__ tab)
{
    int idx = blockIdx.x * 256 + threadIdx.x;   // 0..65535
    int s = idx >> 5, i = idx & 31;
    float inv = expf(-(float)i * 0.2878231366242553f);   // 10000^(-i/32)
    float ang = (float)s * inv;
    tab[idx] = make_float2(cosf(ang), sinf(ang));
}

// ---------------------------------------------------------------------------
// Both weight transposes in one launch.
// grid.x 0..95 -> Wqkv cols; 96..127 -> Wout cols.  grid.y = k0/32.
// ---------------------------------------------------------------------------
__global__ __launch_bounds__(256) void transpose_cvt2(
    const float* __restrict__ W1, const float* __restrict__ W2,
    _Float16* __restrict__ T1, _Float16* __restrict__ T2)
{
    __shared__ float t[32][33];
    const float* W;
    _Float16* T;
    int N, n0;
    if (blockIdx.x < 96) { W = W1; T = T1; N = N_QKV; n0 = blockIdx.x * 32; }
    else                 { W = W2; T = T2; N = DMODEL; n0 = (blockIdx.x - 96) * 32; }
    const int K = DMODEL, k0 = blockIdx.y * 32;
    const int tx = threadIdx.x & 31;
    const int ty = threadIdx.x >> 5;

    #pragma unroll
    for (int i = 0; i < 4; ++i)
        t[ty + i * 8][tx] = W[(size_t)(k0 + ty + i * 8) * N + n0 + tx];
    __syncthreads();
    #pragma unroll
    for (int i = 0; i < 4; ++i) {
        int n = n0 + ty + i * 8;
        T[(size_t)n * K + k0 + tx] = (_Float16)t[tx][ty + i * 8];
    }
}

// ---------------------------------------------------------------------------
// fp16 GEMM, global_load_lds staging, BK=64 (128B LDS rows, 8 granules).
// Source-granule swizzle gran = (lane&7)^(lane>>3): LDS[row][slot] holds
// global granule slot^(row&7); reads use slot=(kh*4+g)^(row&7) -> involution
// verified both sides (rule #21).  Barriers halved vs BK=32; 2x MFMA/sync.
// 4 waves 2x2, wave tile (BM/2)x(BN/2).
// ---------------------------------------------------------------------------
template<int BM, int BN, bool RES, bool F16OUT>
__global__ __launch_bounds__(256) void gemm_lds(
    const _Float16* __restrict__ A, const _Float16* __restrict__ B,
    const float* __restrict__ resid, void* __restrict__ Cout,
    int M, int N, int K)
{
    constexpr int WM = BM / 2, WN = BN / 2;
    constexpr int MI = WM / 16, NJ = WN / 16;
    constexpr int PA = BM * 8 / 256, PB = BN * 8 / 256;   // staging passes

    __shared__ _Float16 As[BM * 64];
    __shared__ _Float16 Bs[BN * 64];

    const int tid = threadIdx.x;
    const int w = tid >> 6, lane = tid & 63;
    const int m16 = lane & 15, g = lane >> 4;
    const int wr = w >> 1, wc = w & 1;
    const int bm = blockIdx.y * BM, bn = blockIdx.x * BN;

    const int sgran = (lane & 7) ^ (lane >> 3);   // source granule (swizzled)

    f32x4 acc[MI][NJ];
    #pragma unroll
    for (int i = 0; i < MI; ++i)
        #pragma unroll
        for (int j = 0; j < NJ; ++j) acc[i][j] = (f32x4)(0.0f);

    for (int kt = 0; kt < K / 64; ++kt) {
        const int k0 = kt * 64;
        __syncthreads();          // prior reads done; LDS safe to overwrite
        #pragma unroll
        for (int p = 0; p < PA; ++p) {
            int row = (p * 256 + tid) >> 3;
            __builtin_amdgcn_global_load_lds(
                (gas_void*)&A[(size_t)(bm + row) * K + k0 + sgran * 8],
                (las_void*)&As[(p * 256 + w * 64) * 8], 16, 0, 0);
        }
        #pragma unroll
        for (int p = 0; p < PB; ++p) {
            int row = (p * 256 + tid) >> 3;
            __builtin_amdgcn_global_load_lds(
                (gas_void*)&B[(size_t)(bn + row) * K + k0 + sgran * 8],
                (las_void*)&Bs[(p * 256 + w * 64) * 8], 16, 0, 0);
        }
        __syncthreads();          // compiler drains vmcnt before barrier

        #pragma unroll
        for (int kh = 0; kh < 2; ++kh) {
            f16x8 af[MI], bf_[NJ];
            #pragma unroll
            for (int i = 0; i < MI; ++i) {
                int row = wr * WM + i * 16 + m16;
                af[i] = *(const f16x8*)&As[row * 64 + (((kh * 4 + g) ^ (row & 7)) << 3)];
            }
            #pragma unroll
            for (int j = 0; j < NJ; ++j) {
                int row = wc * WN + j * 16 + m16;
                bf_[j] = *(const f16x8*)&Bs[row * 64 + (((kh * 4 + g) ^ (row & 7)) << 3)];
            }
            #pragma unroll
            for (int j = 0; j < NJ; ++j)
                #pragma unroll
                for (int i = 0; i < MI; ++i)
                    acc[i][j] = __builtin_amdgcn_mfma_f32_16x16x32_f16(
                        af[i], bf_[j], acc[i][j], 0, 0, 0);
        }
    }

    // epilogue: C/D map col = lane&15, row = 4*(lane>>4)+reg (HW-verified)
    const int g4 = g * 4;
    #pragma unroll
    for (int i = 0; i < MI; ++i)
        #pragma unroll
        for (int j = 0; j < NJ; ++j) {
            int col = bn + wc * WN + j * 16 + m16;
            #pragma unroll
            for (int r = 0; r < 4; ++r) {
                int row = bm + wr * WM + i * 16 + g4 + r;
                float val = acc[i][j][r];
                if constexpr (F16OUT) {
                    ((_Float16*)Cout)[(size_t)row * N + col] = (_Float16)val;
                } else {
                    if (RES) val += resid[(size_t)row * N + col];
                    ((float*)Cout)[(size_t)row * N + col] = val;
                }
            }
        }
}

// ---------------------------------------------------------------------------
// Fused prep: qkv f16 [s][3072] -> rope'd q (pre-scaled 1/8), k as f16
// [h][s][64], and V transposed to vT [h][d][s] bf16.  One pass over qkv.
// ---------------------------------------------------------------------------
__global__ __launch_bounds__(256) void prep_qkv(
    const _Float16* __restrict__ qkv, const float2* __restrict__ tab,
    _Float16* __restrict__ qf, _Float16* __restrict__ kf,
    unsigned short* __restrict__ vT)
{
    __shared__ _Float16 vt[64][72];
    const int s0 = blockIdx.x * 64;
    const int h  = blockIdx.y;
    const int tid = threadIdx.x;

    #pragma unroll
    for (int p = 0; p < 2; ++p) {
        int u = p * 256 + tid;
        int sl = u >> 3;              // 0..63
        int d0 = (u & 7) * 8;         // 0..56
        int s = s0 + sl;
        const _Float16* rowp = qkv + (size_t)s * N_QKV;

        f16x8 qv = *(const f16x8*)&rowp[h * 64 + d0];
        f16x8 kv = *(const f16x8*)&rowp[DMODEL + h * 64 + d0];
        int pd = (d0 < 32) ? d0 + 32 : d0 - 32;
        f16x8 qp_ = *(const f16x8*)&rowp[h * 64 + pd];
        f16x8 kp_ = *(const f16x8*)&rowp[DMODEL + h * 64 + pd];
        float sgn = (d0 < 32) ? -1.0f : 1.0f;

        f16x8 qo, ko;
        #pragma unroll
        for (int j = 0; j < 8; ++j) {
            float2 cs = tab[s * 32 + ((d0 + j) & 31)];
            float qr = (float)qv[j] * cs.x + sgn * (float)qp_[j] * cs.y;
            float kr = (float)kv[j] * cs.x + sgn * (float)kp_[j] * cs.y;
            qo[j] = (_Float16)(qr * 0.125f);
            ko[j] = (_Float16)kr;
        }
        size_t o = ((size_t)h * S_LEN + s) * HDIM + d0;
        *(f16x8*)&qf[o] = qo;
        *(f16x8*)&kf[o] = ko;

        f16x8 vv = *(const f16x8*)&rowp[2 * DMODEL + h * 64 + d0];
        #pragma unroll
        for (int j = 0; j < 8; ++j) vt[sl][d0 + j] = vv[j];
    }
    __syncthreads();
    #pragma unroll
    for (int p = 0; p < 2; ++p) {
        int u = p * 256 + tid;
        int d = u >> 3, sb = (u & 7) * 8;
        s16x8 o;
        #pragma unroll
        for (int i = 0; i < 8; ++i) o[i] = (short)f2bf((float)vt[sb + i][d]);
        *(s16x8*)&vT[((size_t)h * HDIM + d) * S_LEN + s0 + sb] = o;
    }
}

// ---------------------------------------------------------------------------
// MFMA flash-style windowed attention (validated). f16 single-pass scores;
// P,V bf16.  s_setprio around MFMA clusters (T5).  Output f16.
// ---------------------------------------------------------------------------
#define KP 72
__global__ __launch_bounds__(256, 3) void attn_mfma(
    const _Float16* __restrict__ qg, const _Float16* __restrict__ kg,
    const unsigned short* __restrict__ vTg, _Float16* __restrict__ oh)
{
    __shared__ __align__(16) _Float16 Ks[64][KP];
    __shared__ __align__(16) unsigned short Vt[64][KP];
    __shared__ __align__(16) unsigned short Pw[4][16][40];

    const int h   = blockIdx.y;
    const int s0  = blockIdx.x * 64;
    const int tid = threadIdx.x;
    const int w   = tid >> 6, lane = tid & 63;
    const int m16 = lane & 15, g = lane >> 4;
    const int t_base = s0 - 256;

    const int qrow = s0 + w * 16 + m16;
    const _Float16* qp = qg + ((size_t)h * S_LEN + qrow) * HDIM;
    f16x8 qf[2];
    qf[0] = *(const f16x8*)&qp[g * 8];
    qf[1] = *(const f16x8*)&qp[32 + g * 8];

    const int qb_ = w * 16 + m16;
    int lo_b = 256 - s0; if (lo_b < qb_) lo_b = qb_;
    const int hi_b = qb_ + 256;

    f32x4 O[4];
    #pragma unroll
    for (int nt = 0; nt < 4; ++nt) O[nt] = (f32x4)(0.0f);
    float l_r[4] = {0.0f, 0.0f, 0.0f, 0.0f};
    float m_col = -1e30f;

    const int stage_min = (s0 >= 256) ? 0 : ((193 - s0 + 63) >> 6);

    for (int st = stage_min; st < 5; ++st) {
        __syncthreads();
        const int t0s = t_base + st * 64;
        #pragma unroll
        for (int pp = 0; pp < 2; ++pp) {
            int u = tid + pp * 256;
            int row = u >> 3, cb = (u & 7) * 8;
            int t = t0s + row;
            f16x8 kv = {};
            if (t >= 0)
                kv = *(const f16x8*)&kg[((size_t)h * S_LEN + t) * HDIM + cb];
            *(f16x8*)&Ks[row][cb] = kv;
        }
        #pragma unroll
        for (int pp = 0; pp < 2; ++pp) {
            int u = tid + pp * 256;
            int d = u >> 3, kb = (u & 7) * 8;
            int t = t0s + kb;
            s16x8 vv = {};
            if (t >= 0)
                vv = *(const s16x8*)&vTg[((size_t)h * HDIM + d) * S_LEN + t];
            *(s16x8*)&Vt[d][kb] = vv;
        }
        __syncthreads();

        #pragma unroll
        for (int ch = 0; ch < 2; ++ch) {
            f32x4 sc[2];
            __builtin_amdgcn_s_setprio(1);
            #pragma unroll
            for (int kt2 = 0; kt2 < 2; ++kt2) {
                int krow = ch * 32 + kt2 * 16 + m16;
                f16x8 k0 = *(const f16x8*)&Ks[krow][g * 8];
                f16x8 k1 = *(const f16x8*)&Ks[krow][32 + g * 8];
                f32x4 a = (f32x4)(0.0f);
                a = __builtin_amdgcn_mfma_f32_16x16x32_f16(k0, qf[0], a, 0, 0, 0);
                a = __builtin_amdgcn_mfma_f32_16x16x32_f16(k1, qf[1], a, 0, 0, 0);
                sc[kt2] = a;
            }
            __builtin_amdgcn_s_setprio(0);

            float scm[8];
            float pmax = -1e30f;
            #pragma unroll
            for (int kt2 = 0; kt2 < 2; ++kt2)
                #pragma unroll
                for (int r = 0; r < 4; ++r) {
                    int ki = st * 64 + ch * 32 + kt2 * 16 + 4 * g + r;
                    bool vd = (ki >= lo_b) && (ki <= hi_b);
                    float s_ = vd ? sc[kt2][r] : -1e30f;
                    scm[kt2 * 4 + r] = s_;
                    pmax = fmaxf(pmax, s_);
                }
            pmax = fmaxf(pmax, __shfl_xor(pmax, 16));
            pmax = fmaxf(pmax, __shfl_xor(pmax, 32));
            float mnew = fmaxf(m_col, pmax);

            float p[8];
            float psum = 0.0f;
            #pragma unroll
            for (int i = 0; i < 8; ++i) {
                float e = (scm[i] > -9e29f) ? __expf(scm[i] - mnew) : 0.0f;
                p[i] = e;
                psum += e;
            }
            psum += __shfl_xor(psum, 16);
            psum += __shfl_xor(psum, 32);
            float scale = __expf(m_col - mnew);
            m_col = mnew;

            #pragma unroll
            for (int r = 0; r < 4; ++r) {
                float sr = __shfl(scale, 4 * g + r);
                float ps = __shfl(psum, 4 * g + r);
                l_r[r] = l_r[r] * sr + ps;
                O[0][r] *= sr; O[1][r] *= sr; O[2][r] *= sr; O[3][r] *= sr;
            }

            unsigned int d0, d1, d2, d3;
            asm("v_cvt_pk_bf16_f32 %0, %1, %2" : "=v"(d0) : "v"(p[0]), "v"(p[1]));
            asm("v_cvt_pk_bf16_f32 %0, %1, %2" : "=v"(d1) : "v"(p[2]), "v"(p[3]));
            asm("v_cvt_pk_bf16_f32 %0, %1, %2" : "=v"(d2) : "v"(p[4]), "v"(p[5]));
            asm("v_cvt_pk_bf16_f32 %0, %1, %2" : "=v"(d3) : "v"(p[6]), "v"(p[7]));
            *(uint2*)&Pw[w][m16][4 * g]      = make_uint2(d0, d1);
            *(uint2*)&Pw[w][m16][16 + 4 * g] = make_uint2(d2, d3);
            asm volatile("s_waitcnt lgkmcnt(0)" ::: "memory");
            __builtin_amdgcn_sched_barrier(0);
            s16x8 pa = *(const s16x8*)&Pw[w][m16][g * 8];

            __builtin_amdgcn_s_setprio(1);
            #pragma unroll
            for (int nt = 0; nt < 4; ++nt) {
                s16x8 vb = *(const s16x8*)&Vt[nt * 16 + m16][ch * 32 + g * 8];
                O[nt] = __builtin_amdgcn_mfma_f32_16x16x32_bf16(pa, vb, O[nt], 0, 0, 0);
            }
            __builtin_amdgcn_s_setprio(0);
        }
    }

    #pragma unroll
    for (int r = 0; r < 4; ++r) {
        float linv = 1.0f / l_r[r];
        int srow = s0 + w * 16 + 4 * g + r;
        size_t obase = (size_t)srow * DMODEL + h * HDIM;
        #pragma unroll
        for (int nt = 0; nt < 4; ++nt)
            oh[obase + nt * 16 + m16] = (_Float16)(O[nt][r] * linv);
    }
}

// ---------------------------------------------------------------------------
// LayerNorm, one block per row of 1024
// ---------------------------------------------------------------------------
__global__ __launch_bounds__(256) void layernorm_k(
    const float* __restrict__ res, const float* __restrict__ gamma,
    const float* __restrict__ beta, float* __restrict__ y)
{
    const int row  = blockIdx.x;
    const int tid  = threadIdx.x;
    const int wave = tid >> 6;
    const int lane = tid & 63;
    const float* r = res + (size_t)row * DMODEL;

    float4 xv = *(const float4*)&r[tid * 4];
    float ssum = xv.x + xv.y + xv.z + xv.w;
    float ssq  = xv.x * xv.x + xv.y * xv.y + xv.z * xv.z + xv.w * xv.w;

    #pragma unroll
    for (int off = 1; off < 64; off <<= 1) {
        ssum += __shfl_xor(ssum, off);
        ssq  += __shfl_xor(ssq, off);
    }

    __shared__ float wsum[4], wsq[4];
    if (lane == 0) { wsum[wave] = ssum; wsq[wave] = ssq; }
    __syncthreads();

    float tot  = wsum[0] + wsum[1] + wsum[2] + wsum[3];
    float tot2 = wsq[0] + wsq[1] + wsq[2] + wsq[3];
    float mu   = tot * (1.0f / DMODEL);
    float var  = tot2 * (1.0f / DMODEL) - mu * mu;
    float rstd = rsqrtf(var + 1e-5f);

    float4 gm = *(const float4*)&gamma[tid * 4];
    float4 be = *(const float4*)&beta[tid * 4];
    float4 yo;
    yo.x = (xv.x - mu) * rstd * gm.x + be.x;
    yo.y = (xv.y - mu) * rstd * gm.y + be.y;
    yo.z = (xv.z - mu) * rstd * gm.z + be.z;
    yo.w = (xv.w - mu) * rstd * gm.w + be.w;
    *(float4*)&y[(size_t)row * DMODEL + tid * 4] = yo;
}

// ---------------------------------------------------------------------------
extern "C" void kernel_launch(void* const* d_in, const int* in_sizes, int n_in,
                              void* d_out, int out_size, void* d_ws, size_t ws_size,
                              hipStream_t stream) {
    const float* x     = (const float*)d_in[0];
    const float* state = (const float*)d_in[1];
    const float* Wqkv  = (const float*)d_in[2];
    const float* Wout  = (const float*)d_in[3];
    const float* gamma = (const float*)d_in[4];
    const float* beta  = (const float*)d_in[5];
    float* out = (float*)d_out;

    char* base = (char*)d_ws;
    // region A [0, 12.6MB): qkv16; dead after prep_qkv, then overlaid by
    // ah [0,4MB) and res [4,12.4MB).
    _Float16*  qkv16 = (_Float16*)base;                       // [2048][3072] f16
    _Float16*  ah    = (_Float16*)base;                       // [2048][1024] f16
    float*     res   = (float*)(base + 4194304);              // [2048][1024] f32
    _Float16*  qf    = (_Float16*)(base + 16777216);          // [16][2048][64] f16
    _Float16*  kf    = (_Float16*)(base + 20971520);          // [16][2048][64] f16
    unsigned short* vT = (unsigned short*)(base + 25165824);  // [16][64][2048] bf16
    _Float16*  WqkvT = (_Float16*)(base + 29360128);          // [3072][1024] f16
    _Float16*  WoutT = (_Float16*)(base + 35651584);          // [1024][1024] f16
    _Float16*  xh    = (_Float16*)(base + 37748736);          // [2048][1024] f16
    float2*    tab   = (float2*)(base + 41943040);            // [2048][32]

    // --- prep ---
    cvt_f16<<<(S_LEN * DMODEL) / 1024, 256, 0, stream>>>(x, xh);
    rope_tab_k<<<(S_LEN * 32) / 256, 256, 0, stream>>>(tab);
    transpose_cvt2<<<dim3(128, 32), 256, 0, stream>>>(Wqkv, Wout, WqkvT, WoutT);

    // --- QKV projection -> f16 qkv, BK=64 ---
    gemm_lds<128, 128, false, true>
        <<<dim3(N_QKV / 128, S_LEN / 128), 256, 0, stream>>>(
            xh, WqkvT, nullptr, qkv16, S_LEN, N_QKV, DMODEL);

    // --- fused rope + scatter + V-transpose ---
    prep_qkv<<<dim3(S_LEN / 64, NHEADS), 256, 0, stream>>>(
        qkv16, tab, qf, kf, vT);

    // --- MFMA windowed attention ---
    attn_mfma<<<dim3(S_LEN / 64, NHEADS), 256, 0, stream>>>(qf, kf, vT, ah);

    // --- out projection + residual, BK=64 ---
    gemm_lds<64, 64, true, false>
        <<<dim3(DMODEL / 64, S_LEN / 64), 256, 0, stream>>>(
            ah, WoutT, x, res, S_LEN, DMODEL, DMODEL);

    // --- LayerNorm ---
    layernorm_k<<<S_LEN, 256, 0, stream>>>(res, gamma, beta, out);

    // --- state passthrough ---
    hipMemcpyAsync(out + (size_t)S_LEN * DMODEL, state,
                   (size_t)DMODEL * sizeof(float),
                   hipMemcpyDeviceToDevice, stream);
}